// Round 6
// baseline (141.214 us; speedup 1.0000x reference)
//
#include <hip/hip_runtime.h>
#include <hip/hip_bf16.h>
#include <cstdint>

using f32x4  = __attribute__((ext_vector_type(4))) float;
using bf16x8 = __attribute__((ext_vector_type(8))) short;
typedef unsigned short u16;

#define B_DIM 64
#define N_DIM 1024
#define P_DIM 256
#define NTILE 8            // N / 128
#define NUPPER 36          // NTILE*(NTILE+1)/2
#define NB_PREP 16384      // (B*N)/4
#define NB_GRAM 2304       // B * NUPPER  (divisible by 8 — bijective XCD swizzle)
#define BK 32              // K-step: 8 steps over P=256; rows are 64B
#define NSTEP 8

// LDS 16B-chunk position within a 32-u16 row: pos = s ^ ((r>>1)&3).
// bank(r,pos) = 16*(r&1) + 4*pos -> read (16 consecutive r, fixed s) and
// write (4 lanes per r, r=tid>>2) both cover 32 banks at <=2-way (free).
__device__ __forceinline__ int lds_off(int r, int s) {
  return r * 32 + ((s ^ ((r >> 1) & 3)) * 8);
}

// RNE float->bf16
__device__ __forceinline__ u16 f2bf(float f) {
  uint32_t u = __float_as_uint(f);
  u += 0x7fffu + ((u >> 16) & 1u);
  return (u16)(u >> 16);
}

// ---------------------------------------------------------------------------
// Kernel 1: fused BCE partial + per-row sumsq + fp32->bf16 cast. (~HBM floor)
// ---------------------------------------------------------------------------
__global__ __launch_bounds__(256) void prep_kernel(
    const float* __restrict__ X, const float* __restrict__ T,
    u16* __restrict__ Xbf, float* __restrict__ sq,
    float* __restrict__ pb) {
  int tid  = threadIdx.x;
  int w    = tid >> 6, lane = tid & 63;
  size_t row = (size_t)blockIdx.x * 4 + w;
  const float4 xv = ((const float4*)(X + row * P_DIM))[lane];
  const float4 tv = ((const float4*)(T + row * P_DIM))[lane];
  float xs[4] = {xv.x, xv.y, xv.z, xv.w};
  float ts[4] = {tv.x, tv.y, tv.z, tv.w};
  float sqp = 0.f, bce = 0.f;
  ushort4 us;
  u16* up = (u16*)&us;
  #pragma unroll
  for (int i = 0; i < 4; ++i) {
    float x = xs[i];
    sqp += x * x;
    bce += fmaxf(x, 0.f) - x * ts[i] + __logf(1.f + __expf(-fabsf(x)));
    up[i] = f2bf(x);
  }
  ((ushort4*)(Xbf + row * P_DIM))[lane] = us;
  #pragma unroll
  for (int off = 32; off; off >>= 1) {
    sqp += __shfl_down(sqp, off);
    bce += __shfl_down(bce, off);
  }
  __shared__ float red[4];
  if (lane == 0) { sq[row] = sqp; red[w] = bce; }
  __syncthreads();
  if (tid == 0)
    pb[blockIdx.x] = red[0] + red[1] + red[2] + red[3];
}

// ---------------------------------------------------------------------------
// Kernel 2: 128x128 Gram tile via mfma 16x16x32 bf16.
// R6: conflict-free BOTH LDS sides via XOR chunk swizzle (see lds_off) with
// reg-staging: coalesced global_load_dwordx4 (monotone addresses — no R3
// scatter), ds_write_b128 conflict-free, ds_read_b128 conflict-free.
// Double-buffered BK=32 (32KB LDS -> 4 blocks/CU), ONE barrier per step:
// loads for step+1 issued before compute (T14), write to buf^1 needs no
// pre-barrier. Fully unrolled -> static LDS buffer indices.
// ---------------------------------------------------------------------------
__global__ __launch_bounds__(256) void gram_kernel(
    const u16* __restrict__ Xbf, const float* __restrict__ sq,
    float* __restrict__ pd) {
  __shared__ __align__(16) u16 As[2][128 * 32];
  __shared__ __align__(16) u16 Bs[2][128 * 32];
  __shared__ float red[4];

  // XCD-aware swizzle (nwg % 8 == 0): XCD x gets batches [8x, 8x+8).
  int p   = blockIdx.x;
  int blk = (p & 7) * (NB_GRAM / 8) + (p >> 3);
  int b   = blk / NUPPER;
  int t   = blk - b * NUPPER;
  int TI  = 0;
  while (t >= NTILE - TI) { t -= NTILE - TI; ++TI; }
  int TJ = TI + t;                                // TJ >= TI
  const bool diag = (TI == TJ);

  const u16*   Xb  = Xbf + (size_t)b * N_DIM * P_DIM;
  const float* sqb = sq + b * N_DIM;

  int tid  = threadIdx.x;
  int lane = tid & 63;
  int w    = tid >> 6;
  int wr   = w >> 1, wc = w & 1;                  // 2x2 wave grid, 64x64 each
  const bool live = !(diag && wr > wc);

  const int rowA = TI * 128, rowB = TJ * 128;

  // Prefetch epilogue sq values into registers (L2-hit; overlaps K-loop).
  float sqa[16], sqc[4];
  {
    int rb2 = rowA + wr * 64 + (lane >> 4) * 4;
    int cb  = rowB + wc * 64 + (lane & 15);
    #pragma unroll
    for (int m = 0; m < 4; ++m)
      #pragma unroll
      for (int v = 0; v < 4; ++v)
        sqa[m * 4 + v] = sqb[rb2 + m * 16 + v];
    #pragma unroll
    for (int n = 0; n < 4; ++n)
      sqc[n] = sqb[cb + n * 16];
  }

  f32x4 acc[4][4];
  #pragma unroll
  for (int m = 0; m < 4; ++m)
    #pragma unroll
    for (int n = 0; n < 4; ++n)
      acc[m][n] = (f32x4)(0.f);

  // Staging: per step, A tile = 128 rows x 4 chunks (16B) = 512 chunks;
  // thread covers idx = q*256+tid (q=0..1): r = idx>>2, s = idx&3.
  const int sr0 = tid >> 2;           // row for q=0 (q=1: +64)
  const int ss  = tid & 3;            // 16B slot in row
  uint4 ra[2], rb[2];

  auto load_regs = [&](int k0) {
    #pragma unroll
    for (int q = 0; q < 2; ++q) {
      int r = sr0 + q * 64;
      ra[q] = *(const uint4*)(Xb + (size_t)(rowA + r) * P_DIM + k0 + ss * 8);
      if (!diag)
        rb[q] = *(const uint4*)(Xb + (size_t)(rowB + r) * P_DIM + k0 + ss * 8);
    }
  };
  auto write_lds = [&](int buf) {
    #pragma unroll
    for (int q = 0; q < 2; ++q) {
      int r = sr0 + q * 64;
      *(uint4*)&As[buf][lds_off(r, ss)] = ra[q];
      if (!diag)
        *(uint4*)&Bs[buf][lds_off(r, ss)] = rb[q];
    }
  };

  // Prologue: fill buffer 0.
  load_regs(0);
  write_lds(0);
  __syncthreads();

  #pragma unroll
  for (int step = 0; step < NSTEP; ++step) {
    const int cur = step & 1;
    if (step < NSTEP - 1) load_regs((step + 1) * BK);   // issue early (T14)
    if (live) {
      const u16* Ab = As[cur];
      const u16* Bb = diag ? As[cur] : Bs[cur];
      const int s = lane >> 4;                          // k-slot 0..3
      bf16x8 af[4], bfg[4];
      #pragma unroll
      for (int m = 0; m < 4; ++m) {
        int r = wr * 64 + m * 16 + (lane & 15);
        af[m] = *(const bf16x8*)&Ab[lds_off(r, s)];
      }
      #pragma unroll
      for (int n = 0; n < 4; ++n) {
        int r = wc * 64 + n * 16 + (lane & 15);
        bfg[n] = *(const bf16x8*)&Bb[lds_off(r, s)];
      }
      #pragma unroll
      for (int m = 0; m < 4; ++m)
        #pragma unroll
        for (int n = 0; n < 4; ++n)
          acc[m][n] = __builtin_amdgcn_mfma_f32_16x16x32_bf16(
              af[m], bfg[n], acc[m][n], 0, 0, 0);
    }
    if (step < NSTEP - 1) write_lds(cur ^ 1);   // other buffer: no pre-barrier
    __syncthreads();
  }

  // Epilogue: C layout (m89/m91): col = lane&15, row = (lane>>4)*4 + v.
  float s = 0.f;
  if (live) {
    int rb2 = rowA + wr * 64, cb = rowB + wc * 64;
    #pragma unroll
    for (int m = 0; m < 4; ++m) {
      #pragma unroll
      for (int n = 0; n < 4; ++n) {
        #pragma unroll
        for (int v = 0; v < 4; ++v) {
          int gi = rb2 + m * 16 + (lane >> 4) * 4 + v;
          int gj = cb + n * 16 + (lane & 15);
          if (gi < gj) {
            float d2 = sqa[m * 4 + v] + sqc[n] - 2.f * acc[m][n][v];
            s += sqrtf(fmaxf(d2, 0.f));
          }
        }
      }
    }
  }
  #pragma unroll
  for (int off = 32; off; off >>= 1) s += __shfl_down(s, off);
  if (lane == 0) red[w] = s;
  __syncthreads();
  if (tid == 0)
    pd[blockIdx.x] = red[0] + red[1] + red[2] + red[3];
}

// ---------------------------------------------------------------------------
// Kernel 3: reduce partials (double) and combine.
// ---------------------------------------------------------------------------
__global__ __launch_bounds__(256) void finalize_kernel(
    const float* __restrict__ pb, const float* __restrict__ pd,
    float* __restrict__ out) {
  int tid = threadIdx.x;
  double s = 0.0, d = 0.0;
  for (int i = tid; i < NB_PREP; i += 256) s += (double)pb[i];
  for (int i = tid; i < NB_GRAM; i += 256) d += (double)pd[i];
  #pragma unroll
  for (int off = 32; off; off >>= 1) {
    s += __shfl_down(s, off);
    d += __shfl_down(d, off);
  }
  __shared__ double sb[4], db[4];
  int w = tid >> 6, lane = tid & 63;
  if (lane == 0) { sb[w] = s; db[w] = d; }
  __syncthreads();
  if (tid == 0) {
    double bce = (sb[0] + sb[1] + sb[2] + sb[3]) /
                 (double)((size_t)B_DIM * N_DIM * P_DIM);
    double reg = (db[0] + db[1] + db[2] + db[3]) / (double)N_DIM;
    out[0] = (float)(bce - reg);
  }
}

extern "C" void kernel_launch(void* const* d_in, const int* in_sizes, int n_in,
                              void* d_out, int out_size, void* d_ws, size_t ws_size,
                              hipStream_t stream) {
  const float* X = (const float*)d_in[0];
  const float* T = (const float*)d_in[1];
  float* out = (float*)d_out;

  float* pb  = (float*)d_ws;
  float* pd  = (float*)((char*)d_ws + (64 << 10));
  float* sq  = (float*)((char*)d_ws + (80 << 10));
  u16*   Xbf = (u16*)  ((char*)d_ws + (336 << 10));

  prep_kernel<<<NB_PREP, 256, 0, stream>>>(X, T, Xbf, sq, pb);
  gram_kernel<<<NB_GRAM, 256, 0, stream>>>(Xbf, sq, pd);
  finalize_kernel<<<1, 256, 0, stream>>>(pb, pd, out);
}

// Round 7
// 85.265 us; speedup vs baseline: 1.6562x; 1.6562x over previous
//
#include <hip/hip_runtime.h>
#include <hip/hip_bf16.h>
#include <cstdint>

using f32x4  = __attribute__((ext_vector_type(4))) float;
using bf16x8 = __attribute__((ext_vector_type(8))) short;
typedef unsigned short u16;

#define B_DIM 64
#define N_DIM 1024
#define P_DIM 256
#define NTILE 8            // N / 128
#define NUPPER 36          // NTILE*(NTILE+1)/2
#define NB_PREP 16384      // (B*N)/4
#define NB_GRAM 2304       // B * NUPPER  (divisible by 8 — bijective XCD swizzle)
#define BK 32              // K-step: 8 steps over P=256; rows are 64B
#define NSTEP 8

// LDS 16B-chunk position within a 32-u16 row: pos = s ^ ((r>>1)&3).
// bank(r,pos) = 16*(r&1) + 4*pos -> read (16 consecutive r, fixed s) and
// write (4 lanes per r) both cover 32 banks at <=2-way (free). Verified 0
// conflicts in R6.
__device__ __forceinline__ int lds_off(int r, int s) {
  return r * 32 + ((s ^ ((r >> 1) & 3)) * 8);
}

// RNE float->bf16
__device__ __forceinline__ u16 f2bf(float f) {
  uint32_t u = __float_as_uint(f);
  u += 0x7fffu + ((u >> 16) & 1u);
  return (u16)(u >> 16);
}

// ---------------------------------------------------------------------------
// Kernel 1: fused BCE partial + per-row sumsq + fp32->bf16 cast. (~HBM floor)
// ---------------------------------------------------------------------------
__global__ __launch_bounds__(256) void prep_kernel(
    const float* __restrict__ X, const float* __restrict__ T,
    u16* __restrict__ Xbf, float* __restrict__ sq,
    float* __restrict__ pb) {
  int tid  = threadIdx.x;
  int w    = tid >> 6, lane = tid & 63;
  size_t row = (size_t)blockIdx.x * 4 + w;
  const float4 xv = ((const float4*)(X + row * P_DIM))[lane];
  const float4 tv = ((const float4*)(T + row * P_DIM))[lane];
  float xs[4] = {xv.x, xv.y, xv.z, xv.w};
  float ts[4] = {tv.x, tv.y, tv.z, tv.w};
  float sqp = 0.f, bce = 0.f;
  ushort4 us;
  u16* up = (u16*)&us;
  #pragma unroll
  for (int i = 0; i < 4; ++i) {
    float x = xs[i];
    sqp += x * x;
    bce += fmaxf(x, 0.f) - x * ts[i] + __logf(1.f + __expf(-fabsf(x)));
    up[i] = f2bf(x);
  }
  ((ushort4*)(Xbf + row * P_DIM))[lane] = us;
  #pragma unroll
  for (int off = 32; off; off >>= 1) {
    sqp += __shfl_down(sqp, off);
    bce += __shfl_down(bce, off);
  }
  __shared__ float red[4];
  if (lane == 0) { sq[row] = sqp; red[w] = bce; }
  __syncthreads();
  if (tid == 0)
    pb[blockIdx.x] = red[0] + red[1] + red[2] + red[3];
}

// ---------------------------------------------------------------------------
// Kernel 2: 128x128 Gram tile via mfma 16x16x32 bf16.
// R7 = R6 minus the scratch spill: R6's lambda-captured uint4 arrays were
// address-taken -> local memory -> 82 MB of HBM scratch traffic (WRITE_SIZE
// signature across R4/R6 vs R2/R3/R5). Staging regs are now NAMED scalars
// (ra0/ra1/rb0/rb1) written via macros — no arrays, no lambdas.
// Kept from R6 (verified by counters): XOR chunk-swizzle -> 0 bank conflicts
// on both ds_write_b128 and ds_read_b128; coalesced monotone global loads;
// double-buffered BK=32 (32KB LDS); ONE barrier per step; loads issued before
// compute (T14); XCD swizzle (FETCH 17MB); diagonal specialization.
// ---------------------------------------------------------------------------
__global__ __launch_bounds__(256) void gram_kernel(
    const u16* __restrict__ Xbf, const float* __restrict__ sq,
    float* __restrict__ pd) {
  __shared__ __align__(16) u16 As[2][128 * 32];
  __shared__ __align__(16) u16 Bs[2][128 * 32];
  __shared__ float red[4];

  // XCD-aware swizzle (nwg % 8 == 0): XCD x gets batches [8x, 8x+8).
  int p   = blockIdx.x;
  int blk = (p & 7) * (NB_GRAM / 8) + (p >> 3);
  int b   = blk / NUPPER;
  int t   = blk - b * NUPPER;
  int TI  = 0;
  while (t >= NTILE - TI) { t -= NTILE - TI; ++TI; }
  int TJ = TI + t;                                // TJ >= TI
  const bool diag = (TI == TJ);

  const u16*   Xb  = Xbf + (size_t)b * N_DIM * P_DIM;
  const float* sqb = sq + b * N_DIM;

  int tid  = threadIdx.x;
  int lane = tid & 63;
  int w    = tid >> 6;
  int wr   = w >> 1, wc = w & 1;                  // 2x2 wave grid, 64x64 each
  const bool live = !(diag && wr > wc);

  const int rowA = TI * 128, rowB = TJ * 128;

  // Prefetch epilogue sq values into registers (L2-hit; overlaps K-loop).
  float sqa[16], sqc[4];
  {
    int rb2 = rowA + wr * 64 + (lane >> 4) * 4;
    int cb  = rowB + wc * 64 + (lane & 15);
    #pragma unroll
    for (int m = 0; m < 4; ++m)
      #pragma unroll
      for (int v = 0; v < 4; ++v)
        sqa[m * 4 + v] = sqb[rb2 + m * 16 + v];
    #pragma unroll
    for (int n = 0; n < 4; ++n)
      sqc[n] = sqb[cb + n * 16];
  }

  f32x4 acc[4][4];
  #pragma unroll
  for (int m = 0; m < 4; ++m)
    #pragma unroll
    for (int n = 0; n < 4; ++n)
      acc[m][n] = (f32x4)(0.f);

  // Staging geometry: thread covers chunks (r=sr0, s=ss) and (r=sr0+64, s=ss).
  const int sr0 = tid >> 2;           // row 0..63
  const int ss  = tid & 3;            // 16B slot in 64B row
  // Precomputed global pointers (k0 added per step) and LDS write offsets.
  const u16* gA0 = Xb + (size_t)(rowA + sr0)      * P_DIM + ss * 8;
  const u16* gA1 = Xb + (size_t)(rowA + sr0 + 64) * P_DIM + ss * 8;
  const u16* gB0 = Xb + (size_t)(rowB + sr0)      * P_DIM + ss * 8;
  const u16* gB1 = Xb + (size_t)(rowB + sr0 + 64) * P_DIM + ss * 8;
  const int offw0 = lds_off(sr0, ss);
  const int offw1 = lds_off(sr0 + 64, ss);

  uint4 ra0, ra1, rb0, rb1;

#define LOAD_REGS(k0) do {                                        \
    ra0 = *(const uint4*)(gA0 + (k0));                            \
    ra1 = *(const uint4*)(gA1 + (k0));                            \
    if (!diag) {                                                  \
      rb0 = *(const uint4*)(gB0 + (k0));                          \
      rb1 = *(const uint4*)(gB1 + (k0));                          \
    }                                                             \
  } while (0)

#define WRITE_LDS(buf) do {                                       \
    *(uint4*)&As[buf][offw0] = ra0;                               \
    *(uint4*)&As[buf][offw1] = ra1;                               \
    if (!diag) {                                                  \
      *(uint4*)&Bs[buf][offw0] = rb0;                             \
      *(uint4*)&Bs[buf][offw1] = rb1;                             \
    }                                                             \
  } while (0)

  // Prologue: fill buffer 0.
  LOAD_REGS(0);
  WRITE_LDS(0);
  __syncthreads();

  #pragma unroll
  for (int step = 0; step < NSTEP; ++step) {
    const int cur = step & 1;
    if (step < NSTEP - 1) LOAD_REGS((step + 1) * BK);   // issue early (T14)
    if (live) {
      const u16* Ab = As[cur];
      const u16* Bb = diag ? As[cur] : Bs[cur];
      const int s = lane >> 4;                          // k-slot 0..3
      bf16x8 af[4], bfg[4];
      #pragma unroll
      for (int m = 0; m < 4; ++m) {
        int r = wr * 64 + m * 16 + (lane & 15);
        af[m] = *(const bf16x8*)&Ab[lds_off(r, s)];
      }
      #pragma unroll
      for (int n = 0; n < 4; ++n) {
        int r = wc * 64 + n * 16 + (lane & 15);
        bfg[n] = *(const bf16x8*)&Bb[lds_off(r, s)];
      }
      #pragma unroll
      for (int m = 0; m < 4; ++m)
        #pragma unroll
        for (int n = 0; n < 4; ++n)
          acc[m][n] = __builtin_amdgcn_mfma_f32_16x16x32_bf16(
              af[m], bfg[n], acc[m][n], 0, 0, 0);
    }
    if (step < NSTEP - 1) WRITE_LDS(cur ^ 1);   // other buffer: no pre-barrier
    __syncthreads();
  }
#undef LOAD_REGS
#undef WRITE_LDS

  // Epilogue: C layout (m89/m91): col = lane&15, row = (lane>>4)*4 + v.
  float s = 0.f;
  if (live) {
    int rb2 = rowA + wr * 64, cb = rowB + wc * 64;
    #pragma unroll
    for (int m = 0; m < 4; ++m) {
      #pragma unroll
      for (int n = 0; n < 4; ++n) {
        #pragma unroll
        for (int v = 0; v < 4; ++v) {
          int gi = rb2 + m * 16 + (lane >> 4) * 4 + v;
          int gj = cb + n * 16 + (lane & 15);
          if (gi < gj) {
            float d2 = sqa[m * 4 + v] + sqc[n] - 2.f * acc[m][n][v];
            s += sqrtf(fmaxf(d2, 0.f));
          }
        }
      }
    }
  }
  #pragma unroll
  for (int off = 32; off; off >>= 1) s += __shfl_down(s, off);
  if (lane == 0) red[w] = s;
  __syncthreads();
  if (tid == 0)
    pd[blockIdx.x] = red[0] + red[1] + red[2] + red[3];
}

// ---------------------------------------------------------------------------
// Kernel 3: reduce partials (double) and combine.
// ---------------------------------------------------------------------------
__global__ __launch_bounds__(256) void finalize_kernel(
    const float* __restrict__ pb, const float* __restrict__ pd,
    float* __restrict__ out) {
  int tid = threadIdx.x;
  double s = 0.0, d = 0.0;
  for (int i = tid; i < NB_PREP; i += 256) s += (double)pb[i];
  for (int i = tid; i < NB_GRAM; i += 256) d += (double)pd[i];
  #pragma unroll
  for (int off = 32; off; off >>= 1) {
    s += __shfl_down(s, off);
    d += __shfl_down(d, off);
  }
  __shared__ double sb[4], db[4];
  int w = tid >> 6, lane = tid & 63;
  if (lane == 0) { sb[w] = s; db[w] = d; }
  __syncthreads();
  if (tid == 0) {
    double bce = (sb[0] + sb[1] + sb[2] + sb[3]) /
                 (double)((size_t)B_DIM * N_DIM * P_DIM);
    double reg = (db[0] + db[1] + db[2] + db[3]) / (double)N_DIM;
    out[0] = (float)(bce - reg);
  }
}

extern "C" void kernel_launch(void* const* d_in, const int* in_sizes, int n_in,
                              void* d_out, int out_size, void* d_ws, size_t ws_size,
                              hipStream_t stream) {
  const float* X = (const float*)d_in[0];
  const float* T = (const float*)d_in[1];
  float* out = (float*)d_out;

  float* pb  = (float*)d_ws;
  float* pd  = (float*)((char*)d_ws + (64 << 10));
  float* sq  = (float*)((char*)d_ws + (80 << 10));
  u16*   Xbf = (u16*)  ((char*)d_ws + (336 << 10));

  prep_kernel<<<NB_PREP, 256, 0, stream>>>(X, T, Xbf, sq, pb);
  gram_kernel<<<NB_GRAM, 256, 0, stream>>>(Xbf, sq, pd);
  finalize_kernel<<<1, 256, 0, stream>>>(pb, pd, out);
}